// Round 8
// baseline (279.306 us; speedup 1.0000x reference)
//
#include <hip/hip_runtime.h>
#include <math.h>
#include <stdint.h>

// UpsampleFlow3: fused exact 5-NN + softmax(-dist) + weighted flow sum.
// B=4, N=16384, M=4096, K=5, fp32.
//
// Round-10 resubmit (r7 bench was an infra failure: container died twice,
// kernel never ran — same source, unchanged, to get the measurement).
// Structure (post-mortem r9: PASS 269us = 176 knn + ~93 prep/overhead.
// Inst accounting: 12.8K wave-insts avg vs ~1.5K ring-path model -> the
// sliced-brute wide-span fallback (13.8K insts) dominates; phase-1 also
// scanned unpruned (e4=inf) and needed a barrier merge):
//  - per-lane HOME-CELL warm-up: value-only 5-reg ladder over the lane's own
//    query cell -> bw (valid subset upper bound on 5th-best). All prunes use
//    min(e4,bw)+qq. Phase-1 pruned from the start; NO cross-wave merge, NO
//    mid-kernel barrier.
//  - wide-span groups: rotated global Morton walk (all 512 cells, ownership
//    (k&7)==wid, start at box-center cell) with the same per-lane prune.
//    Exact by full coverage; deterministic. Replaces 13.8K-inst brute.
//  - prep: min stored as fenc(-x) via atomicMax -> single zero-memset.

#define KNN 5
#define GRID 8
#define NCELL (GRID * GRID * GRID)
#define SPAN_TH 64
#define SLICES 8
#define BLOCK (SLICES * 64)
#define EPSM 1e-3f

typedef unsigned int u32;

__device__ __forceinline__ float get_inv_sigma(const int* __restrict__ rf) {
    const int ri = rf[0];
    const float sigma = (ri >= 1 && ri <= 1000000) ? (float)ri : __int_as_float(ri);
    return 1.0f / sigma;
}

__device__ __forceinline__ float rfl_f(float v) {
    return __int_as_float(__builtin_amdgcn_readfirstlane(__float_as_int(v)));
}

__device__ __forceinline__ int cid1(float x, float lo, float ich) {
    const int c = (int)floorf((x - lo) * ich);
    return c < 0 ? 0 : (c > GRID - 1 ? GRID - 1 : c);
}

// 3-bit Morton spread: bit i -> bit 3i
__device__ __forceinline__ int sp3(int v) {
    return (v & 1) | ((v & 2) << 2) | ((v & 4) << 4);
}

// monotone float -> u32 (atomicMax-able); fenc(x) for max, fenc(-x) for min.
// All finite encodings are > 0, so a single zero-memset initializes both.
__device__ __forceinline__ u32 fenc(float f) {
    const u32 b = __float_as_uint(f);
    return (b & 0x80000000u) ? ~b : (b | 0x80000000u);
}
__device__ __forceinline__ float fdec(u32 u) {
    return __uint_as_float((u & 0x80000000u) ? (u & 0x7FFFFFFFu) : ~u);
}

// shared grid geometry (identical formula at every use site -> identical fp)
__device__ __forceinline__ void bb_load(const u32* __restrict__ minU,
                                        const u32* __restrict__ maxU, int b,
                                        float& lox, float& loy, float& loz,
                                        float& chx, float& chy, float& chz) {
    const float sc = (1.0f / GRID) * (1.0f + 4e-6f);
    const float Lx = -fdec(minU[b * 3 + 0]);
    const float Ly = -fdec(minU[b * 3 + 1]);
    const float Lz = -fdec(minU[b * 3 + 2]);
    lox = Lx; loy = Ly; loz = Lz;
    chx = (fdec(maxU[b * 3 + 0]) - Lx) * sc + 1e-30f;
    chy = (fdec(maxU[b * 3 + 1]) - Ly) * sc + 1e-30f;
    chz = (fdec(maxU[b * 3 + 2]) - Lz) * sc + 1e-30f;
}

// Compare-exchange: insert candidate (c,ci) into slot (k,ki); larger goes on.
#define CE_FULL(k, ki, c, ci)                          \
    {                                                  \
        const bool sw = (c) < (k);                     \
        const float vmn = fminf(k, c);                 \
        const float vmx = fmaxf(k, c);                 \
        const u32 nki = sw ? (ci) : (ki);              \
        const u32 nci = sw ? (ki) : (ci);              \
        (k) = vmn; (c) = vmx; (ki) = nki; (ci) = nci;  \
    }
#define CE_LAST(k, ki, c, ci)                          \
    {                                                  \
        const bool sw = (c) < (k);                     \
        (ki) = sw ? (ci) : (ki);                       \
        (k) = fminf(k, c);                             \
    }

// exact ladder on d2' = |p|^2 - 2 q.p (qq deferred; order preserved)
#define LAD(P, CI)                                     \
    {                                                  \
        float t_ = qx * (P).x;                         \
        t_ = fmaf(qy, (P).y, t_);                      \
        t_ = fmaf(qz, (P).z, t_);                      \
        float c_ = fmaf(-2.0f, t_, (P).w);             \
        u32 ci_ = (u32)(CI);                           \
        CE_FULL(e0, i0, c_, ci_)                       \
        CE_FULL(e1, i1, c_, ci_)                       \
        CE_FULL(e2, i2, c_, ci_)                       \
        CE_FULL(e3, i3, c_, ci_)                       \
        CE_LAST(e4, i4, c_, ci_)                       \
    }

// ---------------- legacy brute path (ws-too-small fallback) ----------------

__global__ __launch_bounds__(256)
void prep_kernel(const float* __restrict__ sxyz, const int* __restrict__ rf,
                 float4* __restrict__ pts, int M, int total) {
    const int t = blockIdx.x * 256 + threadIdx.x;
    if (t >= total) return;
    const float inv = get_inv_sigma(rf);
    const int b = t / M, m = t - b * M;
    const float* sb = sxyz + (size_t)b * 3 * M;
    const float x = sb[m] * inv;
    const float y = sb[M + m] * inv;
    const float z = sb[2 * M + m] * inv;
    pts[t] = make_float4(x, y, z, fmaf(x, x, fmaf(y, y, z * z)));
}

template <bool USE_PTS>
__global__ __launch_bounds__(BLOCK, 8)
void knn_kernel(const float* __restrict__ xyz,
                const float* __restrict__ sxyz,
                const float* __restrict__ sflow,
                const int* __restrict__ rf,
                const float4* __restrict__ pts,
                float* __restrict__ out,
                int N, int M) {
    __shared__ float sval_d[SLICES * KNN * 64];
    __shared__ u32   sval_i[SLICES * KNN * 64];

    const int tid  = threadIdx.x;
    const int lane = tid & 63;
    const int wid  = tid >> 6;
    const int swid = __builtin_amdgcn_readfirstlane(wid);
    const int gpb  = N / 64;
    const int b    = blockIdx.x / gpb;
    const int grp  = blockIdx.x - b * gpb;
    const int n    = grp * 64 + lane;

    const float inv = get_inv_sigma(rf);
    const float* qb = xyz + (size_t)b * 3 * N;
    const float qx = qb[n] * inv;
    const float qy = qb[N + n] * inv;
    const float qz = qb[2 * N + n] * inv;
    const float qq = fmaf(qx, qx, fmaf(qy, qy, qz * qz));

    const int CH = M / SLICES;
    const int j0 = swid * CH;

    float e0 = 1e30f, e1 = 1e30f, e2 = 1e30f, e3 = 1e30f, e4 = 1e30f;
    u32   i0 = 0, i1 = 0, i2 = 0, i3 = 0, i4 = 0;

    if constexpr (USE_PTS) {
        const float4* __restrict__ P = pts + (size_t)b * M + j0;
#pragma unroll 4
        for (int j = 0; j < CH; ++j) {
            const float4 p = P[j];
            LAD(p, j0 + j)
        }
    } else {
        const float* __restrict__ sb = sxyz + (size_t)b * 3 * M;
#pragma unroll 4
        for (int j = 0; j < CH; ++j) {
            const float px = sb[j0 + j] * inv;
            const float py = sb[M + j0 + j] * inv;
            const float pz = sb[2 * M + j0 + j] * inv;
            const float pw = fmaf(px, px, fmaf(py, py, pz * pz));
            const float4 p = make_float4(px, py, pz, pw);
            LAD(p, j0 + j)
        }
    }

    sval_d[(wid * KNN + 0) * 64 + lane] = e0;  sval_i[(wid * KNN + 0) * 64 + lane] = i0;
    sval_d[(wid * KNN + 1) * 64 + lane] = e1;  sval_i[(wid * KNN + 1) * 64 + lane] = i1;
    sval_d[(wid * KNN + 2) * 64 + lane] = e2;  sval_i[(wid * KNN + 2) * 64 + lane] = i2;
    sval_d[(wid * KNN + 3) * 64 + lane] = e3;  sval_i[(wid * KNN + 3) * 64 + lane] = i3;
    sval_d[(wid * KNN + 4) * 64 + lane] = e4;  sval_i[(wid * KNN + 4) * 64 + lane] = i4;
    __syncthreads();

    if (wid == 0) {
        float m0 = 1e30f, m1 = 1e30f, m2 = 1e30f, m3 = 1e30f, m4 = 1e30f;
        u32   g0 = 0, g1 = 0, g2 = 0, g3 = 0, g4 = 0;
#pragma unroll
        for (int w = 0; w < SLICES; ++w) {
#pragma unroll
            for (int k = 0; k < KNN; ++k) {
                float c = sval_d[(w * KNN + k) * 64 + lane];
                u32  ci = sval_i[(w * KNN + k) * 64 + lane];
                CE_FULL(m0, g0, c, ci)
                CE_FULL(m1, g1, c, ci)
                CE_FULL(m2, g2, c, ci)
                CE_FULL(m3, g3, c, ci)
                CE_LAST(m4, g4, c, ci)
            }
        }

        const float d0 = sqrtf(fmaxf(m0 + qq, 1e-12f));
        const float d1 = sqrtf(fmaxf(m1 + qq, 1e-12f));
        const float d2 = sqrtf(fmaxf(m2 + qq, 1e-12f));
        const float d3 = sqrtf(fmaxf(m3 + qq, 1e-12f));
        const float d4 = sqrtf(fmaxf(m4 + qq, 1e-12f));
        const float w0 = 1.0f;
        const float w1 = expf(d0 - d1);
        const float w2 = expf(d0 - d2);
        const float w3 = expf(d0 - d3);
        const float w4 = expf(d0 - d4);
        const float inv_wsum = 1.0f / (w0 + w1 + w2 + w3 + w4);

        const float* fb = sflow + (size_t)b * 3 * M;
        float ax = 0.f, ay = 0.f, az = 0.f;
        ax = fmaf(w0, fb[g0], ax); ay = fmaf(w0, fb[M + g0], ay); az = fmaf(w0, fb[2 * M + g0], az);
        ax = fmaf(w1, fb[g1], ax); ay = fmaf(w1, fb[M + g1], ay); az = fmaf(w1, fb[2 * M + g1], az);
        ax = fmaf(w2, fb[g2], ax); ay = fmaf(w2, fb[M + g2], ay); az = fmaf(w2, fb[2 * M + g2], az);
        ax = fmaf(w3, fb[g3], ax); ay = fmaf(w3, fb[M + g3], ay); az = fmaf(w3, fb[2 * M + g3], az);
        ax = fmaf(w4, fb[g4], ax); ay = fmaf(w4, fb[M + g4], ay); az = fmaf(w4, fb[2 * M + g4], az);

        float* ob = out + (size_t)b * 3 * N;
        ob[n]         = ax * inv_wsum;
        ob[N + n]     = ay * inv_wsum;
        ob[2 * N + n] = az * inv_wsum;
    }
}

// ---------------- parallel prep: bbox / hist / scan / scatter ----------------

__global__ __launch_bounds__(256)
void bbox_atomic_kernel(const float* __restrict__ sxyz, const int* __restrict__ rf,
                        u32* __restrict__ minU, u32* __restrict__ maxU, int M) {
    const int per = M / 256;                       // blocks per batch
    const int b = blockIdx.x / per;
    const int m = (blockIdx.x - b * per) * 256 + threadIdx.x;
    const float inv = get_inv_sigma(rf);
    const float* sb = sxyz + (size_t)b * 3 * M;
    const float x = sb[m] * inv, y = sb[M + m] * inv, z = sb[2 * M + m] * inv;
    float lx = x, ly = y, lz = z, hx = x, hy = y, hz = z;
#pragma unroll
    for (int mm = 1; mm < 64; mm <<= 1) {
        lx = fminf(lx, __shfl_xor(lx, mm, 64));
        ly = fminf(ly, __shfl_xor(ly, mm, 64));
        lz = fminf(lz, __shfl_xor(lz, mm, 64));
        hx = fmaxf(hx, __shfl_xor(hx, mm, 64));
        hy = fmaxf(hy, __shfl_xor(hy, mm, 64));
        hz = fmaxf(hz, __shfl_xor(hz, mm, 64));
    }
    if ((threadIdx.x & 63) == 0) {
        // min stored as fenc(-x) with atomicMax (zero-init valid for both)
        atomicMax(&minU[b * 3 + 0], fenc(-lx));
        atomicMax(&minU[b * 3 + 1], fenc(-ly));
        atomicMax(&minU[b * 3 + 2], fenc(-lz));
        atomicMax(&maxU[b * 3 + 0], fenc(hx));
        atomicMax(&maxU[b * 3 + 1], fenc(hy));
        atomicMax(&maxU[b * 3 + 2], fenc(hz));
    }
}

__global__ __launch_bounds__(256)
void hist_kernel2(const float* __restrict__ xyz, const float* __restrict__ sxyz,
                  const int* __restrict__ rf, const u32* __restrict__ minU,
                  const u32* __restrict__ maxU, int* __restrict__ histAll,
                  int N, int M, int B) {
    const int t = blockIdx.x * 256 + threadIdx.x;
    const int TC = B * M;
    const float inv = get_inv_sigma(rf);
    float x, y, z; int b, slice;
    if (t < TC) {
        b = t / M; const int i = t - b * M;
        const float* sb = sxyz + (size_t)b * 3 * M;
        x = sb[i] * inv; y = sb[M + i] * inv; z = sb[2 * M + i] * inv;
        slice = b;
    } else if (t < TC + B * N) {
        const int t2 = t - TC;
        b = t2 / N; const int i = t2 - b * N;
        const float* qb = xyz + (size_t)b * 3 * N;
        x = qb[i] * inv; y = qb[N + i] * inv; z = qb[2 * N + i] * inv;
        slice = B + b;
    } else return;
    float lox, loy, loz, chx, chy, chz;
    bb_load(minU, maxU, b, lox, loy, loz, chx, chy, chz);
    const int cell = (sp3(cid1(x, lox, 1.0f / chx)) << 2) |
                     (sp3(cid1(y, loy, 1.0f / chy)) << 1) |
                      sp3(cid1(z, loz, 1.0f / chz));
    atomicAdd(&histAll[(size_t)slice * NCELL + cell], 1);
}

__global__ __launch_bounds__(NCELL)
void scan_kernel2(const int* __restrict__ histAll, int2* __restrict__ off2C,
                  int* __restrict__ curAll, int B) {
    __shared__ int sc[NCELL];
    const int s = blockIdx.x;          // 0..2B-1
    const int t = threadIdx.x;         // 0..NCELL-1
    const int h = histAll[(size_t)s * NCELL + t];
    sc[t] = h;
    __syncthreads();
    for (int d = 1; d < NCELL; d <<= 1) {
        const int v = (t >= d) ? sc[t - d] : 0;
        __syncthreads();
        sc[t] += v;
        __syncthreads();
    }
    const int excl = sc[t] - h;
    curAll[(size_t)s * NCELL + t] = excl;
    if (s < B) off2C[(size_t)s * NCELL + t] = make_int2(excl, excl + h);
}

__global__ __launch_bounds__(256)
void scatter_kernel2(const float* __restrict__ xyz, const float* __restrict__ sxyz,
                     const int* __restrict__ rf, const u32* __restrict__ minU,
                     const u32* __restrict__ maxU, int* __restrict__ curAll,
                     float4* __restrict__ ptsS, float4* __restrict__ qS,
                     int* __restrict__ idxS, int N, int M, int B) {
    const int t = blockIdx.x * 256 + threadIdx.x;
    const int TC = B * M;
    const float inv = get_inv_sigma(rf);
    float x, y, z; int b, i, slice;
    bool isQ;
    if (t < TC) {
        b = t / M; i = t - b * M;
        const float* sb = sxyz + (size_t)b * 3 * M;
        x = sb[i] * inv; y = sb[M + i] * inv; z = sb[2 * M + i] * inv;
        slice = b; isQ = false;
    } else if (t < TC + B * N) {
        const int t2 = t - TC;
        b = t2 / N; i = t2 - b * N;
        const float* qb = xyz + (size_t)b * 3 * N;
        x = qb[i] * inv; y = qb[N + i] * inv; z = qb[2 * N + i] * inv;
        slice = B + b; isQ = true;
    } else return;
    float lox, loy, loz, chx, chy, chz;
    bb_load(minU, maxU, b, lox, loy, loz, chx, chy, chz);
    const int cell = (sp3(cid1(x, lox, 1.0f / chx)) << 2) |
                     (sp3(cid1(y, loy, 1.0f / chy)) << 1) |
                      sp3(cid1(z, loz, 1.0f / chz));
    const int slot = atomicAdd(&curAll[(size_t)slice * NCELL + cell], 1);
    if (isQ) {
        qS[(size_t)b * N + slot] = make_float4(x, y, z, __int_as_float(i));
    } else {
        ptsS[(size_t)b * M + slot] = make_float4(x, y, z, fmaf(x, x, fmaf(y, y, z * z)));
        idxS[(size_t)b * M + slot] = i;
    }
}

// ---------------- main grid kNN: warm-up bound + pruned rings / global walk ----------------

// scan all candidates of cell CELLIDX through the exact ladder
#define CELLSCAN(CELLIDX)                                                       \
    {                                                                           \
        const int2 oo_ = off2b[CELLIDX];                                        \
        const int base_ = __builtin_amdgcn_readfirstlane(oo_.x);                \
        const int end_ = __builtin_amdgcn_readfirstlane(oo_.y);                 \
        int j_ = base_;                                                         \
        for (; j_ + 4 <= end_; j_ += 4) {                                       \
            const float4 p0_ = Pb[j_];                                          \
            const float4 p1_ = Pb[j_ + 1];                                      \
            const float4 p2_ = Pb[j_ + 2];                                      \
            const float4 p3_ = Pb[j_ + 3];                                      \
            LAD(p0_, j_) LAD(p1_, j_ + 1)                                       \
            LAD(p2_, j_ + 2) LAD(p3_, j_ + 3)                                   \
        }                                                                       \
        for (; j_ < end_; ++j_) {                                               \
            const float4 pp_ = Pb[j_];                                          \
            LAD(pp_, j_)                                                        \
        }                                                                       \
    }

// per-lane z-cell test + scan (ring path). needs dxy2, mxy in scope.
#define CELLP(CZ)                                                               \
    {                                                                           \
        const float glz_ = fmaf((float)(CZ), chz, loz);                         \
        const float cqz_ = fminf(fmaxf(qz, glz_), glz_ + chz);                  \
        const float dzl_ = qz - cqz_;                                           \
        const float d3_ = fmaf(dzl_, dzl_, dxy2);                               \
        const float cmp_ = fmaf(fminf(e4, bw) + qq, 1.00001f, EPSM);            \
        if (!__all(d3_ > cmp_)) {                                               \
            CELLSCAN(mxy | sp3(CZ))                                             \
        }                                                                       \
    }

__global__ __launch_bounds__(BLOCK, 8)
void knn_grid8_kernel(const float4* __restrict__ qS, const float4* __restrict__ ptsS,
                      const int* __restrict__ idxS, const int2* __restrict__ off2C,
                      const u32* __restrict__ minU, const u32* __restrict__ maxU,
                      const float* __restrict__ sflow,
                      float* __restrict__ out, int N, int M) {
    __shared__ float sval_d[SLICES * KNN * 64];   // 10 KB
    __shared__ u32   sval_i[SLICES * KNN * 64];   // 10 KB

    const int tid  = threadIdx.x;
    const int lane = tid & 63;
    const int wid  = tid >> 6;
    const int gpb  = N >> 6;
    const int b    = blockIdx.x / gpb;
    const int grp  = blockIdx.x - b * gpb;

    const float4 q4 = qS[(size_t)b * N + grp * 64 + lane];
    const float qx = q4.x, qy = q4.y, qz = q4.z;
    const int n = __float_as_int(q4.w);
    const float qq = fmaf(qx, qx, fmaf(qy, qy, qz * qz));

    // wave AABB -> span box / ring geometry (pruning itself is per-lane)
    float wlx = qx, wly = qy, wlz = qz, whx = qx, why = qy, whz = qz;
#pragma unroll
    for (int m = 1; m < 64; m <<= 1) {
        wlx = fminf(wlx, __shfl_xor(wlx, m, 64));
        whx = fmaxf(whx, __shfl_xor(whx, m, 64));
        wly = fminf(wly, __shfl_xor(wly, m, 64));
        why = fmaxf(why, __shfl_xor(why, m, 64));
        wlz = fminf(wlz, __shfl_xor(wlz, m, 64));
        whz = fmaxf(whz, __shfl_xor(whz, m, 64));
    }
    wlx = rfl_f(wlx) - EPSM; whx = rfl_f(whx) + EPSM;
    wly = rfl_f(wly) - EPSM; why = rfl_f(why) + EPSM;
    wlz = rfl_f(wlz) - EPSM; whz = rfl_f(whz) + EPSM;

    float lox, loy, loz, chx, chy, chz;
    bb_load(minU, maxU, b, lox, loy, loz, chx, chy, chz);
    const float hmin = fminf(chx, fminf(chy, chz));

    const int clx = cid1(wlx, lox, 1.0f / chx), cxh = cid1(whx, lox, 1.0f / chx);
    const int cly = cid1(wly, loy, 1.0f / chy), cyh = cid1(why, loy, 1.0f / chy);
    const int clz = cid1(wlz, loz, 1.0f / chz), czh = cid1(whz, loz, 1.0f / chz);

    float e0 = 1e30f, e1 = 1e30f, e2 = 1e30f, e3 = 1e30f, e4 = 1e30f;
    u32   i0 = 0, i1 = 0, i2 = 0, i3 = 0, i4 = 0;

    const float4* __restrict__ Pb = ptsS + (size_t)b * M;
    const int2* __restrict__ off2b = off2C + (size_t)b * NCELL;

    // ---- per-lane home-cell warm-up: value-only ladder -> bound bw ----
    // bw >= lane's true 5th-best d2' (subset bound); real ladder untouched,
    // so no duplicate-candidate hazard when the walk re-scans the home cell.
    float bw;
    {
        const int hcell = (sp3(cid1(qx, lox, 1.0f / chx)) << 2) |
                          (sp3(cid1(qy, loy, 1.0f / chy)) << 1) |
                           sp3(cid1(qz, loz, 1.0f / chz));
        const int2 ho = off2b[hcell];              // per-lane (divergent) load
        float v0 = 1e30f, v1 = 1e30f, v2 = 1e30f, v3 = 1e30f, v4 = 1e30f;
        for (int j = ho.x; j < ho.y; ++j) {        // divergent trip count: ok
            const float4 p = Pb[j];
            float t = qx * p.x;
            t = fmaf(qy, p.y, t);
            t = fmaf(qz, p.z, t);
            float c = fmaf(-2.0f, t, p.w);
            float mn;
            mn = fminf(v0, c); c = fmaxf(v0, c); v0 = mn;
            mn = fminf(v1, c); c = fmaxf(v1, c); v1 = mn;
            mn = fminf(v2, c); c = fmaxf(v2, c); v2 = mn;
            mn = fminf(v3, c); c = fmaxf(v3, c); v3 = mn;
            v4 = fminf(v4, c);
        }
        bw = v4;
    }

    const int span = (cxh - clx + 1) * (cyh - cly + 1) * (czh - clz + 1);
    if (span > SPAN_TH) {
        // ---- rotated global Morton walk (wide-span groups): all cells,
        // per-lane pruned, ownership (k&7)==wid, start at box-center cell.
        // Exact by full coverage; deterministic (fixed order, no atomics).
        const int ccx = (clx + cxh) >> 1, ccy = (cly + cyh) >> 1, ccz = (clz + czh) >> 1;
        const int c0 = (sp3(ccx) << 2) | (sp3(ccy) << 1) | sp3(ccz);
        for (int k = wid; k < NCELL; k += SLICES) {
            const int c = (c0 + k) & (NCELL - 1);
            const int cx = ((c >> 2) & 1) | ((c >> 4) & 2) | ((c >> 6) & 4);
            const int cy = ((c >> 1) & 1) | ((c >> 3) & 2) | ((c >> 5) & 4);
            const int cz = (c & 1) | ((c >> 2) & 2) | ((c >> 4) & 4);
            const float glx = fmaf((float)cx, chx, lox);
            const float gly = fmaf((float)cy, chy, loy);
            const float glz = fmaf((float)cz, chz, loz);
            const float dxl = qx - fminf(fmaxf(qx, glx), glx + chx);
            const float dyl = qy - fminf(fmaxf(qy, gly), gly + chy);
            const float dzl = qz - fminf(fmaxf(qz, glz), glz + chz);
            const float d3 = fmaf(dzl, dzl, fmaf(dyl, dyl, dxl * dxl));
            const float cmp = fmaf(fminf(e4, bw) + qq, 1.00001f, EPSM);
            if (!__all(d3 > cmp)) {
                CELLSCAN(c)
            }
        }
    } else {
        int ctr = 0;
        // ---- phase 1: span-box scan (ownership round-robin, pruned by bw) ----
        for (int cx = clx; cx <= cxh; ++cx) {
            const float glx = fmaf((float)cx, chx, lox);
            const float cqx = fminf(fmaxf(qx, glx), glx + chx);
            const float dxl = qx - cqx;
            const float dxx = dxl * dxl;
            const int mx = sp3(cx) << 2;
            for (int cy = cly; cy <= cyh; ++cy) {
                const float gly = fmaf((float)cy, chy, loy);
                const float cqy = fminf(fmaxf(qy, gly), gly + chy);
                const float dyl = qy - cqy;
                const float dxy2 = fmaf(dyl, dyl, dxx);
                const int mxy = mx | (sp3(cy) << 1);
                for (int cz = clz; cz <= czh; ++cz) {
                    if (((ctr++) & 7) == wid) { CELLP(cz) }
                }
            }
        }
        // ---- phase 2: expanding rings; termination from own-wave lane-max
        // of min(e4,bw)+qq (deterministic, no cross-wave state). ----
        float TwR = 1e30f;
        for (int r = 1; r <= GRID; ++r) {
            float own = fminf(e4, bw) + qq;
#pragma unroll
            for (int mm = 1; mm < 64; mm <<= 1) own = fmaxf(own, __shfl_xor(own, mm, 64));
            TwR = fminf(TwR, rfl_f(own));
            if (r >= 2) {
                const float bd = (float)(r - 1) * hmin - EPSM;
                if (bd > 0.0f && bd * bd > fmaf(TwR, 1.00001f, EPSM)) break;
            }
            const int x0 = clx - r < 0 ? 0 : clx - r;
            const int x1 = cxh + r > GRID - 1 ? GRID - 1 : cxh + r;
            const int y0 = cly - r < 0 ? 0 : cly - r;
            const int y1 = cyh + r > GRID - 1 ? GRID - 1 : cyh + r;
            const int z0 = clz - r < 0 ? 0 : clz - r;
            const int z1 = czh + r > GRID - 1 ? GRID - 1 : czh + r;
            for (int cx = x0; cx <= x1; ++cx) {
                const int rx = cx < clx ? clx - cx : (cx > cxh ? cx - cxh : 0);
                const float glx = fmaf((float)cx, chx, lox);
                const float cqx = fminf(fmaxf(qx, glx), glx + chx);
                const float dxl = qx - cqx;
                const float dxx = dxl * dxl;
                const int mx = sp3(cx) << 2;
                for (int cy = y0; cy <= y1; ++cy) {
                    const int ry = cy < cly ? cly - cy : (cy > cyh ? cy - cyh : 0);
                    if (((ctr++) & 7) == wid) {
                        const float gly = fmaf((float)cy, chy, loy);
                        const float cqy = fminf(fmaxf(qy, gly), gly + chy);
                        const float dyl = qy - cqy;
                        const float dxy2 = fmaf(dyl, dyl, dxx);
                        const float cmpc = fmaf(fminf(e4, bw) + qq, 1.00001f, EPSM);
                        if (!__all(dxy2 > cmpc)) {
                            const int mxy = mx | (sp3(cy) << 1);
                            if ((rx > ry ? rx : ry) == r) {
                                for (int cz = z0; cz <= z1; ++cz) { CELLP(cz) }
                            } else {
                                if (clz - r >= 0) { CELLP(clz - r) }
                                if (czh + r <= GRID - 1) { CELLP(czh + r) }
                            }
                        }
                    }
                }
            }
        }
    }

    sval_d[(wid * KNN + 0) * 64 + lane] = e0;  sval_i[(wid * KNN + 0) * 64 + lane] = i0;
    sval_d[(wid * KNN + 1) * 64 + lane] = e1;  sval_i[(wid * KNN + 1) * 64 + lane] = i1;
    sval_d[(wid * KNN + 2) * 64 + lane] = e2;  sval_i[(wid * KNN + 2) * 64 + lane] = i2;
    sval_d[(wid * KNN + 3) * 64 + lane] = e3;  sval_i[(wid * KNN + 3) * 64 + lane] = i3;
    sval_d[(wid * KNN + 4) * 64 + lane] = e4;  sval_i[(wid * KNN + 4) * 64 + lane] = i4;
    __syncthreads();

    if (wid == 0) {
        float m0 = 1e30f, m1 = 1e30f, m2 = 1e30f, m3 = 1e30f, m4 = 1e30f;
        u32 g0 = 0, g1 = 0, g2 = 0, g3 = 0, g4 = 0;
#pragma unroll
        for (int w = 0; w < SLICES; ++w) {
#pragma unroll
            for (int k = 0; k < KNN; ++k) {
                float c = sval_d[(w * KNN + k) * 64 + lane];
                u32 ci = sval_i[(w * KNN + k) * 64 + lane];
                CE_FULL(m0, g0, c, ci)
                CE_FULL(m1, g1, c, ci)
                CE_FULL(m2, g2, c, ci)
                CE_FULL(m3, g3, c, ci)
                CE_LAST(m4, g4, c, ci)
            }
        }

        const float d0 = sqrtf(fmaxf(m0 + qq, 1e-12f));
        const float d1 = sqrtf(fmaxf(m1 + qq, 1e-12f));
        const float d2 = sqrtf(fmaxf(m2 + qq, 1e-12f));
        const float d3 = sqrtf(fmaxf(m3 + qq, 1e-12f));
        const float d4 = sqrtf(fmaxf(m4 + qq, 1e-12f));
        const float w0 = 1.0f;
        const float w1 = expf(d0 - d1);
        const float w2 = expf(d0 - d2);
        const float w3 = expf(d0 - d3);
        const float w4 = expf(d0 - d4);
        const float inv_wsum = 1.0f / (w0 + w1 + w2 + w3 + w4);

        const int* __restrict__ idxb = idxS + (size_t)b * M;
        const int o0 = idxb[g0], o1 = idxb[g1], o2 = idxb[g2], o3 = idxb[g3], o4 = idxb[g4];
        const float* fb = sflow + (size_t)b * 3 * M;
        float ax = 0.f, ay = 0.f, az = 0.f;
        ax = fmaf(w0, fb[o0], ax); ay = fmaf(w0, fb[M + o0], ay); az = fmaf(w0, fb[2 * M + o0], az);
        ax = fmaf(w1, fb[o1], ax); ay = fmaf(w1, fb[M + o1], ay); az = fmaf(w1, fb[2 * M + o1], az);
        ax = fmaf(w2, fb[o2], ax); ay = fmaf(w2, fb[M + o2], ay); az = fmaf(w2, fb[2 * M + o2], az);
        ax = fmaf(w3, fb[o3], ax); ay = fmaf(w3, fb[M + o3], ay); az = fmaf(w3, fb[2 * M + o3], az);
        ax = fmaf(w4, fb[o4], ax); ay = fmaf(w4, fb[M + o4], ay); az = fmaf(w4, fb[2 * M + o4], az);

        float* ob = out + (size_t)b * 3 * N;
        ob[n]         = ax * inv_wsum;
        ob[N + n]     = ay * inv_wsum;
        ob[2 * N + n] = az * inv_wsum;
    }
}

extern "C" void kernel_launch(void* const* d_in, const int* in_sizes, int n_in,
                              void* d_out, int out_size, void* d_ws, size_t ws_size,
                              hipStream_t stream) {
    const float* xyz   = (const float*)d_in[0];
    const float* sxyz  = (const float*)d_in[1];
    const float* sflow = (const float*)d_in[2];
    const int*   rf    = (const int*)d_in[3];

    const int B = 4;
    const int N = in_sizes[0] / (3 * B);    // 16384
    const int M = in_sizes[1] / (3 * B);    // 4096
    float* out = (float*)d_out;

    // workspace layout: minU/maxU/histAll contiguous -> ONE zero-memset
    size_t o = 0;
    float4* ptsS  = (float4*)((char*)d_ws + o); o += (size_t)B * M * sizeof(float4);
    float4* qS    = (float4*)((char*)d_ws + o); o += (size_t)B * N * sizeof(float4);
    int*   idxS   = (int*)((char*)d_ws + o);    o += (size_t)B * M * 4;
    u32*   minU   = (u32*)((char*)d_ws + o);    o += (size_t)B * 3 * 4;
    u32*   maxU   = (u32*)((char*)d_ws + o);    o += (size_t)B * 3 * 4;
    int*   histAll= (int*)((char*)d_ws + o);    o += (size_t)2 * B * NCELL * 4;
    int*   curAll = (int*)((char*)d_ws + o);    o += (size_t)2 * B * NCELL * 4;
    int2*  off2C  = (int2*)((char*)d_ws + o);   o += (size_t)B * NCELL * 8;
    const size_t need = o;

    if (ws_size >= need && (N % 64) == 0 && (M % 256) == 0) {
        const int total = B * (M + N);
        hipMemsetAsync(minU, 0x00,
                       (size_t)B * 3 * 4 * 2 + (size_t)2 * B * NCELL * 4, stream);
        bbox_atomic_kernel<<<dim3(B * (M / 256)), dim3(256), 0, stream>>>(
            sxyz, rf, minU, maxU, M);
        hist_kernel2<<<dim3((total + 255) / 256), dim3(256), 0, stream>>>(
            xyz, sxyz, rf, minU, maxU, histAll, N, M, B);
        scan_kernel2<<<dim3(2 * B), dim3(NCELL), 0, stream>>>(
            histAll, off2C, curAll, B);
        scatter_kernel2<<<dim3((total + 255) / 256), dim3(256), 0, stream>>>(
            xyz, sxyz, rf, minU, maxU, curAll, ptsS, qS, idxS, N, M, B);
        knn_grid8_kernel<<<dim3(B * (N / 64)), dim3(BLOCK), 0, stream>>>(
            qS, ptsS, idxS, off2C, minU, maxU, sflow, out, N, M);
    } else {
        const dim3 grid(B * (N / 64));
        const dim3 block(BLOCK);
        const size_t needOld = (size_t)B * M * sizeof(float4);
        if (ws_size >= needOld) {
            float4* pts = (float4*)d_ws;
            prep_kernel<<<dim3((B * M + 255) / 256), dim3(256), 0, stream>>>(
                sxyz, rf, pts, M, B * M);
            knn_kernel<true><<<grid, block, 0, stream>>>(xyz, sxyz, sflow, rf, pts, out, N, M);
        } else {
            knn_kernel<false><<<grid, block, 0, stream>>>(xyz, sxyz, sflow, rf, nullptr, out, N, M);
        }
    }
}